// Round 8
// baseline (260.081 us; speedup 1.0000x reference)
//
#include <hip/hip_runtime.h>

#define DEV __device__ __forceinline__

typedef __bf16 bf16x8 __attribute__((ext_vector_type(8)));
typedef float f32x4 __attribute__((ext_vector_type(4)));
typedef float f32x16 __attribute__((ext_vector_type(16)));
typedef unsigned int u32x2 __attribute__((ext_vector_type(2)));

static constexpr int Tn = 2048;
static constexpr int Dn = 1024;
static constexpr int NHn = 32;
static constexpr int Mn = 2 * Tn;  // B*T = 4096
static constexpr float QSCALE = 0.17677669529663687f * 1.4426950408889634f;  // 1/sqrt(32)*log2e

// native RTNE cast: compiler emits v_cvt_pk_bf16_f32 (1 op vs 3 int ops)
DEV unsigned short f2bf(float f) {
    return __builtin_bit_cast(unsigned short, (__bf16)f);
}

// pack 2 f32 -> 1 u32 of 2 bf16
DEV unsigned pkbf(float lo, float hi) {
    unsigned short l = __builtin_bit_cast(unsigned short, (__bf16)lo);
    unsigned short h = __builtin_bit_cast(unsigned short, (__bf16)hi);
    return (unsigned)l | ((unsigned)h << 16);
}

#define GPTR(p) ((const __attribute__((address_space(1))) void*)(p))
#define LPTR(p) ((__attribute__((address_space(3))) void*)(p))

// ---------------- single fused cast: x (1M float4) + 4 weights (1M float4) ----------------
__global__ __launch_bounds__(256) void cast_all(
    const float* __restrict__ x, const float* __restrict__ Wq, const float* __restrict__ Wk,
    const float* __restrict__ Wv, const float* __restrict__ Wp,
    unsigned short* __restrict__ xb, unsigned short* __restrict__ wall) {
    int i = blockIdx.x * 256 + threadIdx.x;  // [0, 2M)
    const float* src;
    ushort4* dst;
    if (i < (1 << 20)) {
        src = x + (size_t)i * 4;
        dst = reinterpret_cast<ushort4*>(xb) + i;
    } else {
        int j = i - (1 << 20);
        int sel = j >> 18, off = j & ((1 << 18) - 1);
        const float* w = (sel == 0) ? Wq : (sel == 1) ? Wk : (sel == 2) ? Wv : Wp;
        src = w + (size_t)off * 4;
        dst = reinterpret_cast<ushort4*>(wall) + ((size_t)sel << 18) + off;
    }
    float4 v = *reinterpret_cast<const float4*>(src);
    ushort4 o;
    o.x = f2bf(v.x); o.y = f2bf(v.y); o.z = f2bf(v.z); o.w = f2bf(v.w);
    *dst = o;
}

// ---------------- fused QKV GEMM (m97 pattern) + RMSNorm/RoPE/relayout epilogue ----------------
// z=0: Q -> rms+rope+gain+exp2-scale -> Qn (b,h,t,d)
// z=1: K -> rms+rope              -> Kn (b,h,t,d)
// z=2: V -> transpose store        -> Vt (b,h,d,t)
__global__ __launch_bounds__(256) void gemm_qkv(
    const unsigned short* __restrict__ A, const unsigned short* __restrict__ Wall,
    unsigned short* __restrict__ Qn, unsigned short* __restrict__ Kn, unsigned short* __restrict__ Vt,
    const float* __restrict__ gain, const float* __restrict__ cosp, const float* __restrict__ sinp) {
    const int z = blockIdx.z;
    const unsigned short* Bm = Wall + (size_t)z * (Dn * Dn);
    const int m0 = blockIdx.x * 128, n0 = blockIdx.y * 128;
    const int tid = threadIdx.x, w = tid >> 6, l = tid & 63;
    const int wm = w & 1, wn = w >> 1, lm = l & 15, quad = l >> 4;

    __shared__ __align__(16) unsigned short As[128 * 32];  // lane-linear, no padding (global_load_lds)
    __shared__ __align__(16) unsigned short Bs[128 * 32];

    f32x4 acc[4][4] = {};

    const int r0 = (w * 2 + 0) * 16 + (l >> 2);
    const int r1 = (w * 2 + 1) * 16 + (l >> 2);
    const int c0 = (l & 3) * 8;
    const unsigned short* gA0 = A + (long)(m0 + r0) * Dn + c0;
    const unsigned short* gA1 = A + (long)(m0 + r1) * Dn + c0;
    const unsigned short* gB0 = Bm + (long)(n0 + r0) * Dn + c0;
    const unsigned short* gB1 = Bm + (long)(n0 + r1) * Dn + c0;
    unsigned short* lA0 = As + (w * 2 + 0) * 16 * 32;
    unsigned short* lA1 = As + (w * 2 + 1) * 16 * 32;
    unsigned short* lB0 = Bs + (w * 2 + 0) * 16 * 32;
    unsigned short* lB1 = Bs + (w * 2 + 1) * 16 * 32;

    for (int kk = 0; kk < Dn; kk += 32) {
        __builtin_amdgcn_global_load_lds(GPTR(gA0 + kk), LPTR(lA0), 16, 0, 0);
        __builtin_amdgcn_global_load_lds(GPTR(gA1 + kk), LPTR(lA1), 16, 0, 0);
        __builtin_amdgcn_global_load_lds(GPTR(gB0 + kk), LPTR(lB0), 16, 0, 0);
        __builtin_amdgcn_global_load_lds(GPTR(gB1 + kk), LPTR(lB1), 16, 0, 0);
        __syncthreads();
        bf16x8 af[4], bfv[4];
#pragma unroll
        for (int mt = 0; mt < 4; ++mt)
            af[mt] = __builtin_bit_cast(bf16x8,
                *reinterpret_cast<const uint4*>(As + (wm * 64 + mt * 16 + lm) * 32 + quad * 8));
#pragma unroll
        for (int nt = 0; nt < 4; ++nt)
            bfv[nt] = __builtin_bit_cast(bf16x8,
                *reinterpret_cast<const uint4*>(Bs + (wn * 64 + nt * 16 + lm) * 32 + quad * 8));
#pragma unroll
        for (int mt = 0; mt < 4; ++mt)
#pragma unroll
            for (int nt = 0; nt < 4; ++nt)
                acc[mt][nt] = __builtin_amdgcn_mfma_f32_16x16x32_bf16(af[mt], bfv[nt], acc[mt][nt], 0, 0, 0);
        __syncthreads();
    }

    if (z == 2) {
        // V transpose-store: rows r=0..3 are consecutive t -> ushort4
#pragma unroll
        for (int mt = 0; mt < 4; ++mt) {
            int row0 = m0 + wm * 64 + mt * 16 + quad * 4;
            int b_ = row0 >> 11, t_ = row0 & (Tn - 1);
#pragma unroll
            for (int nt = 0; nt < 4; ++nt) {
                int col = n0 + wn * 64 + nt * 16 + lm;
                int hh = col >> 5, dd = col & 31;
                ushort4 o4;
                o4.x = f2bf(acc[mt][nt][0]); o4.y = f2bf(acc[mt][nt][1]);
                o4.z = f2bf(acc[mt][nt][2]); o4.w = f2bf(acc[mt][nt][3]);
                *reinterpret_cast<ushort4*>(&Vt[((long)(b_ * NHn + hh) * 32 + dd) * Tn + t_]) = o4;
            }
        }
    } else {
        unsigned short* dst = z ? Kn : Qn;
#pragma unroll
        for (int mt = 0; mt < 4; ++mt)
#pragma unroll
            for (int r = 0; r < 4; ++r) {
                int row = m0 + wm * 64 + mt * 16 + quad * 4 + r;
                int b_ = row >> 11, t_ = row & (Tn - 1);
                float c = cosp[t_ * 16 + lm], s = sinp[t_ * 16 + lm];
#pragma unroll
                for (int g = 0; g < 2; ++g) {
                    // head = 32 cols = nt in {2g, 2g+1}; RoPE pair (d, d+16) lives in same lane
                    float x1 = acc[mt][2 * g][r], x2 = acc[mt][2 * g + 1][r];
                    float ssv = x1 * x1 + x2 * x2;
#pragma unroll
                    for (int off = 8; off >= 1; off >>= 1) ssv += __shfl_xor(ssv, off, 16);
                    float rinv = rsqrtf(ssv * (1.0f / 32.0f) + 1e-6f);
                    x1 *= rinv; x2 *= rinv;
                    float o1 = x1 * c - x2 * s;
                    float o2 = x2 * c + x1 * s;
                    int hh = (n0 + wn * 64 + g * 32) >> 5;
                    if (z == 0) { float gs = gain[hh] * QSCALE; o1 *= gs; o2 *= gs; }
                    long base = ((long)(b_ * NHn + hh) * Tn + t_) * 32;
                    dst[base + lm] = f2bf(o1);
                    dst[base + 16 + lm] = f2bf(o2);
                }
            }
    }
}

// ---------------- proj GEMM (m97 pattern), fp32 out ----------------
__global__ __launch_bounds__(256) void gemm_proj(
    const unsigned short* __restrict__ A, const unsigned short* __restrict__ Bm,
    float* __restrict__ C) {
    const int m0 = blockIdx.x * 128, n0 = blockIdx.y * 128;
    const int tid = threadIdx.x, w = tid >> 6, l = tid & 63;
    const int wm = w & 1, wn = w >> 1, lm = l & 15, quad = l >> 4;

    __shared__ __align__(16) unsigned short As[128 * 32];
    __shared__ __align__(16) unsigned short Bs[128 * 32];

    f32x4 acc[4][4] = {};

    const int r0 = (w * 2 + 0) * 16 + (l >> 2);
    const int r1 = (w * 2 + 1) * 16 + (l >> 2);
    const int c0 = (l & 3) * 8;
    const unsigned short* gA0 = A + (long)(m0 + r0) * Dn + c0;
    const unsigned short* gA1 = A + (long)(m0 + r1) * Dn + c0;
    const unsigned short* gB0 = Bm + (long)(n0 + r0) * Dn + c0;
    const unsigned short* gB1 = Bm + (long)(n0 + r1) * Dn + c0;
    unsigned short* lA0 = As + (w * 2 + 0) * 16 * 32;
    unsigned short* lA1 = As + (w * 2 + 1) * 16 * 32;
    unsigned short* lB0 = Bs + (w * 2 + 0) * 16 * 32;
    unsigned short* lB1 = Bs + (w * 2 + 1) * 16 * 32;

    for (int kk = 0; kk < Dn; kk += 32) {
        __builtin_amdgcn_global_load_lds(GPTR(gA0 + kk), LPTR(lA0), 16, 0, 0);
        __builtin_amdgcn_global_load_lds(GPTR(gA1 + kk), LPTR(lA1), 16, 0, 0);
        __builtin_amdgcn_global_load_lds(GPTR(gB0 + kk), LPTR(lB0), 16, 0, 0);
        __builtin_amdgcn_global_load_lds(GPTR(gB1 + kk), LPTR(lB1), 16, 0, 0);
        __syncthreads();
        bf16x8 af[4], bfv[4];
#pragma unroll
        for (int mt = 0; mt < 4; ++mt)
            af[mt] = __builtin_bit_cast(bf16x8,
                *reinterpret_cast<const uint4*>(As + (wm * 64 + mt * 16 + lm) * 32 + quad * 8));
#pragma unroll
        for (int nt = 0; nt < 4; ++nt)
            bfv[nt] = __builtin_bit_cast(bf16x8,
                *reinterpret_cast<const uint4*>(Bs + (wn * 64 + nt * 16 + lm) * 32 + quad * 8));
#pragma unroll
        for (int mt = 0; mt < 4; ++mt)
#pragma unroll
            for (int nt = 0; nt < 4; ++nt)
                acc[mt][nt] = __builtin_amdgcn_mfma_f32_16x16x32_bf16(af[mt], bfv[nt], acc[mt][nt], 0, 0, 0);
        __syncthreads();
    }
#pragma unroll
    for (int mt = 0; mt < 4; ++mt)
#pragma unroll
        for (int nt = 0; nt < 4; ++nt)
#pragma unroll
            for (int r = 0; r < 4; ++r) {
                int rg = m0 + wm * 64 + mt * 16 + quad * 4 + r;
                int cg = n0 + wn * 64 + nt * 16 + lm;
                C[(long)rg * Dn + cg] = acc[mt][nt][r];
            }
}

// ---------------- flash attention: swapped-QK 32x32 in-register softmax + LDS-staged K/V ----------------
// R5 post-mortem: LDS staging verified (+13 us); now VALUBusy 62% at only 2 waves/SIMD (grid was
// the occupancy limiter: 512 blocks = 2 blocks/CU). This round: ONE q-tile per block, grid
// (16, NH, B) = 1024 blocks = 4 blocks/CU = 4 waves/SIMD. Per-wave q-rows stays 32 (R1 lesson)
// and staged K/V traffic is IDENTICAL (pairing only balanced load, never shared staging).
// Balance via LPT dispatch order: qb = 15 - bx, so 32-tile blocks launch first, 2-tile blocks
// drain the tail. Resources: VGPR 76 (6 w/SIMD ok), LDS 16 KB (10 blocks/CU ok).
// Slot permutation (rule #21): LDS linear; DMA SOURCE applies inverse perm; reads apply perm.
__global__ __launch_bounds__(256) void attn(
    const unsigned short* __restrict__ Qn, const unsigned short* __restrict__ Kn,
    const unsigned short* __restrict__ Vt, unsigned short* __restrict__ Y) {
    const int bx = blockIdx.x, h = blockIdx.y, b = blockIdx.z;
    const int tid = threadIdx.x, w = tid >> 6, l = tid & 63;
    const int lr = l & 31, hf = l >> 5;  // lane-row (q-row / d), half-select
    const long bh = b * NHn + h;
    const unsigned short* Qh = Qn + bh * Tn * 32;
    const unsigned short* Kh = Kn + bh * Tn * 32;
    const unsigned short* Vh = Vt + bh * 32 * Tn;

    __shared__ __align__(16) unsigned short KT[2][2048];  // 64 k-rows x 64B, slot-permuted
    __shared__ __align__(16) unsigned short VT[2][2048];  // 32 d-rows x 128B, slot-permuted

    // ---- static per-lane DMA source offsets (inverse permutation) ----
    // K: wave w fills slots o = w*64 + lane; row = o>>2, sl = o&3, s = (sl - (row>>1)) & 3
    const int k_row = w * 16 + (l >> 2);
    const int k_s = ((l & 3) - (k_row >> 1)) & 3;
    const unsigned short* ksrc = Kh + k_row * 32 + k_s * 8;  // + k0*32 per tile
    // V: slots o = w*64 + lane; row = o>>3, sl = o&7, s = (sl - row) & 7
    const int v_row = w * 8 + (l >> 3);
    const int v_s = ((l & 7) - v_row) & 7;
    const unsigned short* vsrc = Vh + (long)v_row * Tn + v_s * 8;  // + k0 per tile

    const int qb = 15 - bx;  // LPT: heaviest q-tile (qb=15, 32 k-tiles) dispatches first
    const int q0 = qb * 128 + w * 32;

    // Q fragments (B-operand of swapped QK^T): lane lr holds q-row q0+lr
    bf16x8 qf[2];
    qf[0] = __builtin_bit_cast(bf16x8,
        *reinterpret_cast<const uint4*>(Qh + (q0 + lr) * 32 + hf * 8));
    qf[1] = __builtin_bit_cast(bf16x8,
        *reinterpret_cast<const uint4*>(Qh + (q0 + lr) * 32 + 16 + hf * 8));
    float ss = 0.f;
#pragma unroll
    for (int j = 0; j < 8; ++j) {
        float v0 = (float)qf[0][j], v1 = (float)qf[1][j];
        ss += v0 * v0 + v1 * v1;
    }
    ss += __shfl_xor(ss, 32);
    const float Mv = __builtin_sqrtf(ss * 32.0f);  // |q_row| * |k|max (rms -> |k| <= sqrt(32))
    f32x16 negC;
#pragma unroll
    for (int i = 0; i < 16; ++i) negC[i] = -Mv;

    float lsum = 0.f;
    f32x16 o = {};  // O[qrow in regs][d = lane&31]

    const int kend = q0 + 31;
    const int ntb = 2 * qb + 2;  // block-uniform tile count (covers all 4 waves' causal range)

    auto stage = [&](int buf, int k0) {
        __builtin_amdgcn_global_load_lds(GPTR(ksrc + k0 * 32), LPTR(&KT[buf][w * 512]), 16, 0, 0);
        __builtin_amdgcn_global_load_lds(GPTR(vsrc + k0), LPTR(&VT[buf][w * 512]), 16, 0, 0);
    };

    auto compute_t = [&](int buf, int k0) {
#pragma unroll
        for (int sub = 0; sub < 2; ++sub) {
            const int ks = k0 + sub * 32;
            if (ks > kend) continue;  // wave-uniform
            const int krow = sub * 32 + lr;
            const int sl0 = ((0 + hf) + (krow >> 1)) & 3;  // dt=0: s = hf
            const int sl1 = ((2 + hf) + (krow >> 1)) & 3;  // dt=1: s = 2+hf
            bf16x8 k0f = __builtin_bit_cast(bf16x8,
                *reinterpret_cast<const uint4*>(&KT[buf][krow * 32 + sl0 * 8]));
            bf16x8 k1f = __builtin_bit_cast(bf16x8,
                *reinterpret_cast<const uint4*>(&KT[buf][krow * 32 + sl1 * 8]));
            f32x16 st = __builtin_amdgcn_mfma_f32_32x32x16_bf16(k0f, qf[0], negC, 0, 0, 0);
            st = __builtin_amdgcn_mfma_f32_32x32x16_bf16(k1f, qf[1], st, 0, 0, 0);
            const bool full = (ks + 31) <= q0;
            const int qrow = q0 + lr;
            float p[16];
#pragma unroll
            for (int r = 0; r < 16; ++r) {
                float pv = __builtin_amdgcn_exp2f(st[r]);
                if (!full) {
                    int kg = ks + (r & 3) + 8 * (r >> 2) + 4 * hf;
                    pv = (kg <= qrow) ? pv : 0.0f;
                }
                p[r] = pv;
            }
            float t0 = (p[0] + p[1]) + (p[2] + p[3]);
            float t1 = (p[4] + p[5]) + (p[6] + p[7]);
            float t2 = (p[8] + p[9]) + (p[10] + p[11]);
            float t3 = (p[12] + p[13]) + (p[14] + p[15]);
            lsum += (t0 + t1) + (t2 + t3);
            unsigned A0 = pkbf(p[0], p[1]), A1 = pkbf(p[2], p[3]);
            unsigned B0 = pkbf(p[4], p[5]), B1 = pkbf(p[6], p[7]);
            unsigned A2 = pkbf(p[8], p[9]), A3 = pkbf(p[10], p[11]);
            unsigned B2 = pkbf(p[12], p[13]), B3 = pkbf(p[14], p[15]);
            u32x2 s0 = __builtin_amdgcn_permlane32_swap(A0, B0, false, false);
            u32x2 s1 = __builtin_amdgcn_permlane32_swap(A1, B1, false, false);
            u32x2 s2 = __builtin_amdgcn_permlane32_swap(A2, B2, false, false);
            u32x2 s3 = __builtin_amdgcn_permlane32_swap(A3, B3, false, false);
            uint4 f0; f0.x = s0[0]; f0.y = s1[0]; f0.z = s0[1]; f0.w = s1[1];
            uint4 f1; f1.x = s2[0]; f1.y = s3[0]; f1.z = s2[1]; f1.w = s3[1];
            // V frags: i = sub*2 + kf; s = i*2 + hf; sl = (s + lr) & 7
            const int slv0 = ((sub * 4 + 0 + hf) + lr) & 7;
            const int slv1 = ((sub * 4 + 2 + hf) + lr) & 7;
            bf16x8 v0f = __builtin_bit_cast(bf16x8,
                *reinterpret_cast<const uint4*>(&VT[buf][lr * 64 + slv0 * 8]));
            bf16x8 v1f = __builtin_bit_cast(bf16x8,
                *reinterpret_cast<const uint4*>(&VT[buf][lr * 64 + slv1 * 8]));
            o = __builtin_amdgcn_mfma_f32_32x32x16_bf16(
                __builtin_bit_cast(bf16x8, f0), v0f, o, 0, 0, 0);
            o = __builtin_amdgcn_mfma_f32_32x32x16_bf16(
                __builtin_bit_cast(bf16x8, f1), v1f, o, 0, 0, 0);
        }
    };

    // ---- double-buffered k-loop: barrier -> issue next DMA -> compute current ----
    stage(0, 0);
    int cur = 0;
    for (int ti = 0; ti < ntb; ++ti) {
        __syncthreads();  // drains DMAs for buf[cur] (compiler emits vmcnt(0) before s_barrier)
        if (ti + 1 < ntb) stage(cur ^ 1, (ti + 1) * 64);
        compute_t(cur, ti * 64);
        cur ^= 1;
    }

    // epilogue: l broadcast (qrow lives at lane qrow), normalize, store
    lsum += __shfl_xor(lsum, 32);
    const float inv = 1.0f / lsum;
#pragma unroll
    for (int r = 0; r < 16; ++r) {
        int qr = (r & 3) + 8 * (r >> 2) + 4 * hf;
        float invr = __shfl(inv, qr);
        long base = ((long)(b * Tn + q0 + qr) * NHn + h) * 32;
        Y[base + lr] = f2bf(o[r] * invr);
    }
}

extern "C" void kernel_launch(void* const* d_in, const int* in_sizes, int n_in,
                              void* d_out, int out_size, void* d_ws, size_t ws_size,
                              hipStream_t stream) {
    (void)in_sizes; (void)n_in; (void)out_size; (void)ws_size;
    const float* x = (const float*)d_in[0];
    const float* Wq = (const float*)d_in[1];
    const float* Wk = (const float*)d_in[2];
    const float* Wv = (const float*)d_in[3];
    const float* Wp = (const float*)d_in[4];
    const float* gain = (const float*)d_in[5];
    const float* cosp = (const float*)d_in[6];
    const float* sinp = (const float*)d_in[7];

    char* ws = (char*)d_ws;
    const size_t SZ = (size_t)Mn * Dn * 2;  // 8 MB
    unsigned short* xb = (unsigned short*)ws;
    unsigned short* wall = (unsigned short*)(ws + SZ);  // [Wq|Wk|Wv|Wp], 8 MB
    unsigned short* qn = (unsigned short*)(ws + 2 * SZ);
    unsigned short* kn = qn + (size_t)Mn * Dn;
    unsigned short* vt = kn + (size_t)Mn * Dn;
    unsigned short* ybuf = vt + (size_t)Mn * Dn;
    // total ws: 48 MB

    cast_all<<<8192, 256, 0, stream>>>(x, Wq, Wk, Wv, Wp, xb, wall);

    gemm_qkv<<<dim3(Mn / 128, Dn / 128, 3), 256, 0, stream>>>(
        xb, wall, qn, kn, vt, gain, cosp, sinp);

    attn<<<dim3(16, NHn, 2), 256, 0, stream>>>(qn, kn, vt, ybuf);

    gemm_proj<<<dim3(Mn / 128, Dn / 128), 256, 0, stream>>>(
        ybuf, wall + (size_t)3 * Dn * Dn, (float*)d_out);
}

// Round 9
// 225.750 us; speedup vs baseline: 1.1521x; 1.1521x over previous
//
#include <hip/hip_runtime.h>

#define DEV __device__ __forceinline__

typedef __bf16 bf16x8 __attribute__((ext_vector_type(8)));
typedef float f32x4 __attribute__((ext_vector_type(4)));
typedef float f32x16 __attribute__((ext_vector_type(16)));
typedef unsigned int u32x2 __attribute__((ext_vector_type(2)));

static constexpr int Tn = 2048;
static constexpr int Dn = 1024;
static constexpr int NHn = 32;
static constexpr int Mn = 2 * Tn;  // B*T = 4096
static constexpr float QSCALE = 0.17677669529663687f * 1.4426950408889634f;  // 1/sqrt(32)*log2e

// native RTNE cast: compiler emits v_cvt_pk_bf16_f32 (1 op vs 3 int ops)
DEV unsigned short f2bf(float f) {
    return __builtin_bit_cast(unsigned short, (__bf16)f);
}

// pack 2 f32 -> 1 u32 of 2 bf16
DEV unsigned pkbf(float lo, float hi) {
    unsigned short l = __builtin_bit_cast(unsigned short, (__bf16)lo);
    unsigned short h = __builtin_bit_cast(unsigned short, (__bf16)hi);
    return (unsigned)l | ((unsigned)h << 16);
}

#define GPTR(p) ((const __attribute__((address_space(1))) void*)(p))
#define LPTR(p) ((__attribute__((address_space(3))) void*)(p))

// ---------------- single fused cast: x (1M float4) + 4 weights (1M float4) ----------------
__global__ __launch_bounds__(256) void cast_all(
    const float* __restrict__ x, const float* __restrict__ Wq, const float* __restrict__ Wk,
    const float* __restrict__ Wv, const float* __restrict__ Wp,
    unsigned short* __restrict__ xb, unsigned short* __restrict__ wall) {
    int i = blockIdx.x * 256 + threadIdx.x;  // [0, 2M)
    const float* src;
    ushort4* dst;
    if (i < (1 << 20)) {
        src = x + (size_t)i * 4;
        dst = reinterpret_cast<ushort4*>(xb) + i;
    } else {
        int j = i - (1 << 20);
        int sel = j >> 18, off = j & ((1 << 18) - 1);
        const float* w = (sel == 0) ? Wq : (sel == 1) ? Wk : (sel == 2) ? Wv : Wp;
        src = w + (size_t)off * 4;
        dst = reinterpret_cast<ushort4*>(wall) + ((size_t)sel << 18) + off;
    }
    float4 v = *reinterpret_cast<const float4*>(src);
    ushort4 o;
    o.x = f2bf(v.x); o.y = f2bf(v.y); o.z = f2bf(v.z); o.w = f2bf(v.w);
    *dst = o;
}

// ---------------- fused QKV GEMM (m97 pattern) + RMSNorm/RoPE/relayout epilogue ----------------
// z=0: Q -> rms+rope+gain+exp2-scale -> Qn (b,h,t,d)
// z=1: K -> rms+rope              -> Kn (b,h,t,d)
// z=2: V -> transpose store        -> Vt (b,h,d,t)
__global__ __launch_bounds__(256) void gemm_qkv(
    const unsigned short* __restrict__ A, const unsigned short* __restrict__ Wall,
    unsigned short* __restrict__ Qn, unsigned short* __restrict__ Kn, unsigned short* __restrict__ Vt,
    const float* __restrict__ gain, const float* __restrict__ cosp, const float* __restrict__ sinp) {
    const int z = blockIdx.z;
    const unsigned short* Bm = Wall + (size_t)z * (Dn * Dn);
    const int m0 = blockIdx.x * 128, n0 = blockIdx.y * 128;
    const int tid = threadIdx.x, w = tid >> 6, l = tid & 63;
    const int wm = w & 1, wn = w >> 1, lm = l & 15, quad = l >> 4;

    __shared__ __align__(16) unsigned short As[128 * 32];  // lane-linear, no padding (global_load_lds)
    __shared__ __align__(16) unsigned short Bs[128 * 32];

    f32x4 acc[4][4] = {};

    const int r0 = (w * 2 + 0) * 16 + (l >> 2);
    const int r1 = (w * 2 + 1) * 16 + (l >> 2);
    const int c0 = (l & 3) * 8;
    const unsigned short* gA0 = A + (long)(m0 + r0) * Dn + c0;
    const unsigned short* gA1 = A + (long)(m0 + r1) * Dn + c0;
    const unsigned short* gB0 = Bm + (long)(n0 + r0) * Dn + c0;
    const unsigned short* gB1 = Bm + (long)(n0 + r1) * Dn + c0;
    unsigned short* lA0 = As + (w * 2 + 0) * 16 * 32;
    unsigned short* lA1 = As + (w * 2 + 1) * 16 * 32;
    unsigned short* lB0 = Bs + (w * 2 + 0) * 16 * 32;
    unsigned short* lB1 = Bs + (w * 2 + 1) * 16 * 32;

    for (int kk = 0; kk < Dn; kk += 32) {
        __builtin_amdgcn_global_load_lds(GPTR(gA0 + kk), LPTR(lA0), 16, 0, 0);
        __builtin_amdgcn_global_load_lds(GPTR(gA1 + kk), LPTR(lA1), 16, 0, 0);
        __builtin_amdgcn_global_load_lds(GPTR(gB0 + kk), LPTR(lB0), 16, 0, 0);
        __builtin_amdgcn_global_load_lds(GPTR(gB1 + kk), LPTR(lB1), 16, 0, 0);
        __syncthreads();
        bf16x8 af[4], bfv[4];
#pragma unroll
        for (int mt = 0; mt < 4; ++mt)
            af[mt] = __builtin_bit_cast(bf16x8,
                *reinterpret_cast<const uint4*>(As + (wm * 64 + mt * 16 + lm) * 32 + quad * 8));
#pragma unroll
        for (int nt = 0; nt < 4; ++nt)
            bfv[nt] = __builtin_bit_cast(bf16x8,
                *reinterpret_cast<const uint4*>(Bs + (wn * 64 + nt * 16 + lm) * 32 + quad * 8));
#pragma unroll
        for (int mt = 0; mt < 4; ++mt)
#pragma unroll
            for (int nt = 0; nt < 4; ++nt)
                acc[mt][nt] = __builtin_amdgcn_mfma_f32_16x16x32_bf16(af[mt], bfv[nt], acc[mt][nt], 0, 0, 0);
        __syncthreads();
    }

    if (z == 2) {
        // V transpose-store: rows r=0..3 are consecutive t -> ushort4
#pragma unroll
        for (int mt = 0; mt < 4; ++mt) {
            int row0 = m0 + wm * 64 + mt * 16 + quad * 4;
            int b_ = row0 >> 11, t_ = row0 & (Tn - 1);
#pragma unroll
            for (int nt = 0; nt < 4; ++nt) {
                int col = n0 + wn * 64 + nt * 16 + lm;
                int hh = col >> 5, dd = col & 31;
                ushort4 o4;
                o4.x = f2bf(acc[mt][nt][0]); o4.y = f2bf(acc[mt][nt][1]);
                o4.z = f2bf(acc[mt][nt][2]); o4.w = f2bf(acc[mt][nt][3]);
                *reinterpret_cast<ushort4*>(&Vt[((long)(b_ * NHn + hh) * 32 + dd) * Tn + t_]) = o4;
            }
        }
    } else {
        unsigned short* dst = z ? Kn : Qn;
#pragma unroll
        for (int mt = 0; mt < 4; ++mt)
#pragma unroll
            for (int r = 0; r < 4; ++r) {
                int row = m0 + wm * 64 + mt * 16 + quad * 4 + r;
                int b_ = row >> 11, t_ = row & (Tn - 1);
                float c = cosp[t_ * 16 + lm], s = sinp[t_ * 16 + lm];
#pragma unroll
                for (int g = 0; g < 2; ++g) {
                    // head = 32 cols = nt in {2g, 2g+1}; RoPE pair (d, d+16) lives in same lane
                    float x1 = acc[mt][2 * g][r], x2 = acc[mt][2 * g + 1][r];
                    float ssv = x1 * x1 + x2 * x2;
#pragma unroll
                    for (int off = 8; off >= 1; off >>= 1) ssv += __shfl_xor(ssv, off, 16);
                    float rinv = rsqrtf(ssv * (1.0f / 32.0f) + 1e-6f);
                    x1 *= rinv; x2 *= rinv;
                    float o1 = x1 * c - x2 * s;
                    float o2 = x2 * c + x1 * s;
                    int hh = (n0 + wn * 64 + g * 32) >> 5;
                    if (z == 0) { float gs = gain[hh] * QSCALE; o1 *= gs; o2 *= gs; }
                    long base = ((long)(b_ * NHn + hh) * Tn + t_) * 32;
                    dst[base + lm] = f2bf(o1);
                    dst[base + 16 + lm] = f2bf(o2);
                }
            }
    }
}

// ---------------- proj GEMM (m97 pattern), fp32 out ----------------
__global__ __launch_bounds__(256) void gemm_proj(
    const unsigned short* __restrict__ A, const unsigned short* __restrict__ Bm,
    float* __restrict__ C) {
    const int m0 = blockIdx.x * 128, n0 = blockIdx.y * 128;
    const int tid = threadIdx.x, w = tid >> 6, l = tid & 63;
    const int wm = w & 1, wn = w >> 1, lm = l & 15, quad = l >> 4;

    __shared__ __align__(16) unsigned short As[128 * 32];
    __shared__ __align__(16) unsigned short Bs[128 * 32];

    f32x4 acc[4][4] = {};

    const int r0 = (w * 2 + 0) * 16 + (l >> 2);
    const int r1 = (w * 2 + 1) * 16 + (l >> 2);
    const int c0 = (l & 3) * 8;
    const unsigned short* gA0 = A + (long)(m0 + r0) * Dn + c0;
    const unsigned short* gA1 = A + (long)(m0 + r1) * Dn + c0;
    const unsigned short* gB0 = Bm + (long)(n0 + r0) * Dn + c0;
    const unsigned short* gB1 = Bm + (long)(n0 + r1) * Dn + c0;
    unsigned short* lA0 = As + (w * 2 + 0) * 16 * 32;
    unsigned short* lA1 = As + (w * 2 + 1) * 16 * 32;
    unsigned short* lB0 = Bs + (w * 2 + 0) * 16 * 32;
    unsigned short* lB1 = Bs + (w * 2 + 1) * 16 * 32;

    for (int kk = 0; kk < Dn; kk += 32) {
        __builtin_amdgcn_global_load_lds(GPTR(gA0 + kk), LPTR(lA0), 16, 0, 0);
        __builtin_amdgcn_global_load_lds(GPTR(gA1 + kk), LPTR(lA1), 16, 0, 0);
        __builtin_amdgcn_global_load_lds(GPTR(gB0 + kk), LPTR(lB0), 16, 0, 0);
        __builtin_amdgcn_global_load_lds(GPTR(gB1 + kk), LPTR(lB1), 16, 0, 0);
        __syncthreads();
        bf16x8 af[4], bfv[4];
#pragma unroll
        for (int mt = 0; mt < 4; ++mt)
            af[mt] = __builtin_bit_cast(bf16x8,
                *reinterpret_cast<const uint4*>(As + (wm * 64 + mt * 16 + lm) * 32 + quad * 8));
#pragma unroll
        for (int nt = 0; nt < 4; ++nt)
            bfv[nt] = __builtin_bit_cast(bf16x8,
                *reinterpret_cast<const uint4*>(Bs + (wn * 64 + nt * 16 + lm) * 32 + quad * 8));
#pragma unroll
        for (int mt = 0; mt < 4; ++mt)
#pragma unroll
            for (int nt = 0; nt < 4; ++nt)
                acc[mt][nt] = __builtin_amdgcn_mfma_f32_16x16x32_bf16(af[mt], bfv[nt], acc[mt][nt], 0, 0, 0);
        __syncthreads();
    }
#pragma unroll
    for (int mt = 0; mt < 4; ++mt)
#pragma unroll
        for (int nt = 0; nt < 4; ++nt)
#pragma unroll
            for (int r = 0; r < 4; ++r) {
                int rg = m0 + wm * 64 + mt * 16 + quad * 4 + r;
                int cg = n0 + wn * 64 + nt * 16 + lm;
                C[(long)rg * Dn + cg] = acc[mt][nt][r];
            }
}

// ---------------- flash attention: swapped-QK 32x32, LDS-staged K/V, 8-wave k-split ----------------
// R8 post-mortem: 1024 non-uniform blocks all resident at t=0 -> no backfill, drained tail
// (occupancy FELL to 16.9%). Fix: keep R5's EXACTLY-uniform 512-block pairing, raise waves/CU by
// splitting k INSIDE the block: 512 threads = 8 waves = 4 q-waves (wq: 32 q-rows each, MFMA stays
// full 32x32) x 2 k-groups (kg). Per pass, group 0 stages+computes tiles [0, qb+1), group 1
// [qb+1, 2qb+2) -- equal counts, lockstep barriers. Each group has private double-buffered KT/VT.
// M static => (o, l) partials combine LINEARLY via padded-LDS exchange (R2/R3-proven pattern).
// 16 waves/CU (2 blocks x 8 waves), zero tail, staged bytes identical to R5.
// Plain __launch_bounds__(512): NEVER force a VGPR cap (R2 lesson; spill tell = WRITE_SIZE).
__global__ __launch_bounds__(512) void attn(
    const unsigned short* __restrict__ Qn, const unsigned short* __restrict__ Kn,
    const unsigned short* __restrict__ Vt, unsigned short* __restrict__ Y) {
    const int bx = blockIdx.x, h = blockIdx.y, b = blockIdx.z;
    const int tid = threadIdx.x, w = tid >> 6, l = tid & 63;
    const int wq = w & 3, kg = w >> 2;
    const int lr = l & 31, hf = l >> 5;  // lane-row (q-row / d), half-select
    const long bh = b * NHn + h;
    const unsigned short* Qh = Qn + bh * Tn * 32;
    const unsigned short* Kh = Kn + bh * Tn * 32;
    const unsigned short* Vh = Vt + bh * 32 * Tn;

    __shared__ __align__(16) unsigned short KT[2][2][2048];  // [kg][buf]: 64 k-rows x 64B, slot-permuted
    __shared__ __align__(16) unsigned short VT[2][2][2048];  // [kg][buf]: 32 d-rows x 128B, slot-permuted
    __shared__ float Po[4][64][17];                          // k-group partial exchange (o[16] + lsum)

    // ---- static per-lane DMA source offsets (inverse permutation; wq-based, same per group) ----
    // K: wave fills slots o = wq*64 + lane; row = o>>2, sl = o&3, s = (sl - (row>>1)) & 3
    const int k_row = wq * 16 + (l >> 2);
    const int k_s = ((l & 3) - (k_row >> 1)) & 3;
    const unsigned short* ksrc = Kh + k_row * 32 + k_s * 8;  // + k0*32 per tile
    // V: slots o = wq*64 + lane; row = o>>3, sl = o&7, s = (sl - row) & 7
    const int v_row = wq * 8 + (l >> 3);
    const int v_s = ((l & 7) - v_row) & 7;
    const unsigned short* vsrc = Vh + (long)v_row * Tn + v_s * 8;  // + k0 per tile

    for (int pass = 0; pass < 2; ++pass) {
        const int qb = pass ? (15 - bx) : bx;
        const int q0 = qb * 128 + wq * 32;

        // Q fragments (B-operand of swapped QK^T): lane lr holds q-row q0+lr
        bf16x8 qf[2];
        qf[0] = __builtin_bit_cast(bf16x8,
            *reinterpret_cast<const uint4*>(Qh + (q0 + lr) * 32 + hf * 8));
        qf[1] = __builtin_bit_cast(bf16x8,
            *reinterpret_cast<const uint4*>(Qh + (q0 + lr) * 32 + 16 + hf * 8));
        float ss = 0.f;
#pragma unroll
        for (int j = 0; j < 8; ++j) {
            float v0 = (float)qf[0][j], v1 = (float)qf[1][j];
            ss += v0 * v0 + v1 * v1;
        }
        ss += __shfl_xor(ss, 32);
        const float Mv = __builtin_sqrtf(ss * 32.0f);  // |q_row| * |k|max (rms -> |k| <= sqrt(32))
        f32x16 negC;
#pragma unroll
        for (int i = 0; i < 16; ++i) negC[i] = -Mv;

        float lsum = 0.f;
        f32x16 o = {};  // O[qrow in regs][d = lane&31]

        const int kend = q0 + 31;
        // group tile ranges: [0, qb+1) and [qb+1, 2qb+2): equal counts -> lockstep barriers
        const int cnt = qb + 1;
        const int ts = kg ? cnt : 0;

        auto stage = [&](int buf, int kt) {
            __builtin_amdgcn_global_load_lds(GPTR(ksrc + kt * 64 * 32), LPTR(&KT[kg][buf][wq * 512]), 16, 0, 0);
            __builtin_amdgcn_global_load_lds(GPTR(vsrc + kt * 64), LPTR(&VT[kg][buf][wq * 512]), 16, 0, 0);
        };

        auto compute_t = [&](int buf, int k0) {
#pragma unroll
            for (int sub = 0; sub < 2; ++sub) {
                const int ks = k0 + sub * 32;
                if (ks > kend) continue;  // wave-uniform
                const int krow = sub * 32 + lr;
                const int sl0 = ((0 + hf) + (krow >> 1)) & 3;  // dt=0: s = hf
                const int sl1 = ((2 + hf) + (krow >> 1)) & 3;  // dt=1: s = 2+hf
                bf16x8 k0f = __builtin_bit_cast(bf16x8,
                    *reinterpret_cast<const uint4*>(&KT[kg][buf][krow * 32 + sl0 * 8]));
                bf16x8 k1f = __builtin_bit_cast(bf16x8,
                    *reinterpret_cast<const uint4*>(&KT[kg][buf][krow * 32 + sl1 * 8]));
                f32x16 st = __builtin_amdgcn_mfma_f32_32x32x16_bf16(k0f, qf[0], negC, 0, 0, 0);
                st = __builtin_amdgcn_mfma_f32_32x32x16_bf16(k1f, qf[1], st, 0, 0, 0);
                const bool full = (ks + 31) <= q0;
                const int qrow = q0 + lr;
                float p[16];
#pragma unroll
                for (int r = 0; r < 16; ++r) {
                    float pv = __builtin_amdgcn_exp2f(st[r]);
                    if (!full) {
                        int kgc = ks + (r & 3) + 8 * (r >> 2) + 4 * hf;
                        pv = (kgc <= qrow) ? pv : 0.0f;
                    }
                    p[r] = pv;
                }
                float t0 = (p[0] + p[1]) + (p[2] + p[3]);
                float t1 = (p[4] + p[5]) + (p[6] + p[7]);
                float t2 = (p[8] + p[9]) + (p[10] + p[11]);
                float t3 = (p[12] + p[13]) + (p[14] + p[15]);
                lsum += (t0 + t1) + (t2 + t3);
                unsigned A0 = pkbf(p[0], p[1]), A1 = pkbf(p[2], p[3]);
                unsigned B0 = pkbf(p[4], p[5]), B1 = pkbf(p[6], p[7]);
                unsigned A2 = pkbf(p[8], p[9]), A3 = pkbf(p[10], p[11]);
                unsigned B2 = pkbf(p[12], p[13]), B3 = pkbf(p[14], p[15]);
                u32x2 s0 = __builtin_amdgcn_permlane32_swap(A0, B0, false, false);
                u32x2 s1 = __builtin_amdgcn_permlane32_swap(A1, B1, false, false);
                u32x2 s2 = __builtin_amdgcn_permlane32_swap(A2, B2, false, false);
                u32x2 s3 = __builtin_amdgcn_permlane32_swap(A3, B3, false, false);
                uint4 f0; f0.x = s0[0]; f0.y = s1[0]; f0.z = s0[1]; f0.w = s1[1];
                uint4 f1; f1.x = s2[0]; f1.y = s3[0]; f1.z = s2[1]; f1.w = s3[1];
                // V frags: i = sub*2 + kf; s = i*2 + hf; sl = (s + lr) & 7
                const int slv0 = ((sub * 4 + 0 + hf) + lr) & 7;
                const int slv1 = ((sub * 4 + 2 + hf) + lr) & 7;
                bf16x8 v0f = __builtin_bit_cast(bf16x8,
                    *reinterpret_cast<const uint4*>(&VT[kg][buf][lr * 64 + slv0 * 8]));
                bf16x8 v1f = __builtin_bit_cast(bf16x8,
                    *reinterpret_cast<const uint4*>(&VT[kg][buf][lr * 64 + slv1 * 8]));
                o = __builtin_amdgcn_mfma_f32_32x32x16_bf16(
                    __builtin_bit_cast(bf16x8, f0), v0f, o, 0, 0, 0);
                o = __builtin_amdgcn_mfma_f32_32x32x16_bf16(
                    __builtin_bit_cast(bf16x8, f1), v1f, o, 0, 0, 0);
            }
        };

        // ---- double-buffered k-loop, lockstep across both groups ----
        stage(0, ts);
        int cur = 0;
        for (int i = 0; i < cnt; ++i) {
            __syncthreads();  // drains DMAs for buf[cur] (compiler emits vmcnt(0) before s_barrier)
            if (i + 1 < cnt) stage(cur ^ 1, ts + i + 1);
            compute_t(cur, (ts + i) * 64);
            cur ^= 1;
        }

        // ---- linear partial combine across k-groups (static M => no max merge) ----
        if (kg) {
            float* p = &Po[wq][l][0];
#pragma unroll
            for (int r = 0; r < 16; ++r) p[r] = o[r];
            p[16] = lsum;
        }
        __syncthreads();
        if (!kg) {
            const float* p = &Po[wq][l][0];
            float ls = lsum + p[16];
            ls += __shfl_xor(ls, 32);
            const float inv = 1.0f / ls;
#pragma unroll
            for (int r = 0; r < 16; ++r) {
                int qr = (r & 3) + 8 * (r >> 2) + 4 * hf;
                float invr = __shfl(inv, qr);
                long base = ((long)(b * Tn + q0 + qr) * NHn + h) * 32;
                Y[base + lr] = f2bf((o[r] + p[r]) * invr);
            }
        }
        __syncthreads();  // protect Po + staging buffers before next pass reuses them
    }
}

extern "C" void kernel_launch(void* const* d_in, const int* in_sizes, int n_in,
                              void* d_out, int out_size, void* d_ws, size_t ws_size,
                              hipStream_t stream) {
    (void)in_sizes; (void)n_in; (void)out_size; (void)ws_size;
    const float* x = (const float*)d_in[0];
    const float* Wq = (const float*)d_in[1];
    const float* Wk = (const float*)d_in[2];
    const float* Wv = (const float*)d_in[3];
    const float* Wp = (const float*)d_in[4];
    const float* gain = (const float*)d_in[5];
    const float* cosp = (const float*)d_in[6];
    const float* sinp = (const float*)d_in[7];

    char* ws = (char*)d_ws;
    const size_t SZ = (size_t)Mn * Dn * 2;  // 8 MB
    unsigned short* xb = (unsigned short*)ws;
    unsigned short* wall = (unsigned short*)(ws + SZ);  // [Wq|Wk|Wv|Wp], 8 MB
    unsigned short* qn = (unsigned short*)(ws + 2 * SZ);
    unsigned short* kn = qn + (size_t)Mn * Dn;
    unsigned short* vt = kn + (size_t)Mn * Dn;
    unsigned short* ybuf = vt + (size_t)Mn * Dn;
    // total ws: 48 MB

    cast_all<<<8192, 256, 0, stream>>>(x, Wq, Wk, Wv, Wp, xb, wall);

    gemm_qkv<<<dim3(Mn / 128, Dn / 128, 3), 256, 0, stream>>>(
        xb, wall, qn, kn, vt, gain, cosp, sinp);

    attn<<<dim3(8, NHn, 2), 512, 0, stream>>>(qn, kn, vt, ybuf);

    gemm_proj<<<dim3(Mn / 128, Dn / 128), 256, 0, stream>>>(
        ybuf, wall + (size_t)3 * Dn * Dn, (float*)d_out);
}

// Round 10
// 225.240 us; speedup vs baseline: 1.1547x; 1.0023x over previous
//
#include <hip/hip_runtime.h>

#define DEV __device__ __forceinline__

typedef __bf16 bf16x8 __attribute__((ext_vector_type(8)));
typedef float f32x4 __attribute__((ext_vector_type(4)));
typedef float f32x16 __attribute__((ext_vector_type(16)));
typedef unsigned int u32x2 __attribute__((ext_vector_type(2)));

static constexpr int Tn = 2048;
static constexpr int Dn = 1024;
static constexpr int NHn = 32;
static constexpr int Mn = 2 * Tn;  // B*T = 4096
static constexpr float QSCALE = 0.17677669529663687f * 1.4426950408889634f;  // 1/sqrt(32)*log2e

// native RTNE cast: compiler emits v_cvt_pk_bf16_f32 (1 op vs 3 int ops)
DEV unsigned short f2bf(float f) {
    return __builtin_bit_cast(unsigned short, (__bf16)f);
}

// pack 2 f32 -> 1 u32 of 2 bf16
DEV unsigned pkbf(float lo, float hi) {
    unsigned short l = __builtin_bit_cast(unsigned short, (__bf16)lo);
    unsigned short h = __builtin_bit_cast(unsigned short, (__bf16)hi);
    return (unsigned)l | ((unsigned)h << 16);
}

#define GPTR(p) ((const __attribute__((address_space(1))) void*)(p))
#define LPTR(p) ((__attribute__((address_space(3))) void*)(p))

// ---------------- single fused cast: x (1M float4) + 4 weights (1M float4) ----------------
__global__ __launch_bounds__(256) void cast_all(
    const float* __restrict__ x, const float* __restrict__ Wq, const float* __restrict__ Wk,
    const float* __restrict__ Wv, const float* __restrict__ Wp,
    unsigned short* __restrict__ xb, unsigned short* __restrict__ wall) {
    int i = blockIdx.x * 256 + threadIdx.x;  // [0, 2M)
    const float* src;
    ushort4* dst;
    if (i < (1 << 20)) {
        src = x + (size_t)i * 4;
        dst = reinterpret_cast<ushort4*>(xb) + i;
    } else {
        int j = i - (1 << 20);
        int sel = j >> 18, off = j & ((1 << 18) - 1);
        const float* w = (sel == 0) ? Wq : (sel == 1) ? Wk : (sel == 2) ? Wv : Wp;
        src = w + (size_t)off * 4;
        dst = reinterpret_cast<ushort4*>(wall) + ((size_t)sel << 18) + off;
    }
    float4 v = *reinterpret_cast<const float4*>(src);
    ushort4 o;
    o.x = f2bf(v.x); o.y = f2bf(v.y); o.z = f2bf(v.z); o.w = f2bf(v.w);
    *dst = o;
}

// ---------------- fused QKV GEMM (m97 pattern) + RMSNorm/RoPE/relayout epilogue ----------------
// z=0: Q -> rms+rope+gain+exp2-scale -> Qn (b,h,t,d)
// z=1: K -> rms+rope              -> Kn (b,h,t,d)
// z=2: V -> transpose store        -> Vt (b,h,d,t)
__global__ __launch_bounds__(256) void gemm_qkv(
    const unsigned short* __restrict__ A, const unsigned short* __restrict__ Wall,
    unsigned short* __restrict__ Qn, unsigned short* __restrict__ Kn, unsigned short* __restrict__ Vt,
    const float* __restrict__ gain, const float* __restrict__ cosp, const float* __restrict__ sinp) {
    const int z = blockIdx.z;
    const unsigned short* Bm = Wall + (size_t)z * (Dn * Dn);
    const int m0 = blockIdx.x * 128, n0 = blockIdx.y * 128;
    const int tid = threadIdx.x, w = tid >> 6, l = tid & 63;
    const int wm = w & 1, wn = w >> 1, lm = l & 15, quad = l >> 4;

    __shared__ __align__(16) unsigned short As[128 * 32];  // lane-linear, no padding (global_load_lds)
    __shared__ __align__(16) unsigned short Bs[128 * 32];

    f32x4 acc[4][4] = {};

    const int r0 = (w * 2 + 0) * 16 + (l >> 2);
    const int r1 = (w * 2 + 1) * 16 + (l >> 2);
    const int c0 = (l & 3) * 8;
    const unsigned short* gA0 = A + (long)(m0 + r0) * Dn + c0;
    const unsigned short* gA1 = A + (long)(m0 + r1) * Dn + c0;
    const unsigned short* gB0 = Bm + (long)(n0 + r0) * Dn + c0;
    const unsigned short* gB1 = Bm + (long)(n0 + r1) * Dn + c0;
    unsigned short* lA0 = As + (w * 2 + 0) * 16 * 32;
    unsigned short* lA1 = As + (w * 2 + 1) * 16 * 32;
    unsigned short* lB0 = Bs + (w * 2 + 0) * 16 * 32;
    unsigned short* lB1 = Bs + (w * 2 + 1) * 16 * 32;

    for (int kk = 0; kk < Dn; kk += 32) {
        __builtin_amdgcn_global_load_lds(GPTR(gA0 + kk), LPTR(lA0), 16, 0, 0);
        __builtin_amdgcn_global_load_lds(GPTR(gA1 + kk), LPTR(lA1), 16, 0, 0);
        __builtin_amdgcn_global_load_lds(GPTR(gB0 + kk), LPTR(lB0), 16, 0, 0);
        __builtin_amdgcn_global_load_lds(GPTR(gB1 + kk), LPTR(lB1), 16, 0, 0);
        __syncthreads();
        bf16x8 af[4], bfv[4];
#pragma unroll
        for (int mt = 0; mt < 4; ++mt)
            af[mt] = __builtin_bit_cast(bf16x8,
                *reinterpret_cast<const uint4*>(As + (wm * 64 + mt * 16 + lm) * 32 + quad * 8));
#pragma unroll
        for (int nt = 0; nt < 4; ++nt)
            bfv[nt] = __builtin_bit_cast(bf16x8,
                *reinterpret_cast<const uint4*>(Bs + (wn * 64 + nt * 16 + lm) * 32 + quad * 8));
#pragma unroll
        for (int mt = 0; mt < 4; ++mt)
#pragma unroll
            for (int nt = 0; nt < 4; ++nt)
                acc[mt][nt] = __builtin_amdgcn_mfma_f32_16x16x32_bf16(af[mt], bfv[nt], acc[mt][nt], 0, 0, 0);
        __syncthreads();
    }

    if (z == 2) {
        // V transpose-store: rows r=0..3 are consecutive t -> ushort4
#pragma unroll
        for (int mt = 0; mt < 4; ++mt) {
            int row0 = m0 + wm * 64 + mt * 16 + quad * 4;
            int b_ = row0 >> 11, t_ = row0 & (Tn - 1);
#pragma unroll
            for (int nt = 0; nt < 4; ++nt) {
                int col = n0 + wn * 64 + nt * 16 + lm;
                int hh = col >> 5, dd = col & 31;
                ushort4 o4;
                o4.x = f2bf(acc[mt][nt][0]); o4.y = f2bf(acc[mt][nt][1]);
                o4.z = f2bf(acc[mt][nt][2]); o4.w = f2bf(acc[mt][nt][3]);
                *reinterpret_cast<ushort4*>(&Vt[((long)(b_ * NHn + hh) * 32 + dd) * Tn + t_]) = o4;
            }
        }
    } else {
        unsigned short* dst = z ? Kn : Qn;
#pragma unroll
        for (int mt = 0; mt < 4; ++mt)
#pragma unroll
            for (int r = 0; r < 4; ++r) {
                int row = m0 + wm * 64 + mt * 16 + quad * 4 + r;
                int b_ = row >> 11, t_ = row & (Tn - 1);
                float c = cosp[t_ * 16 + lm], s = sinp[t_ * 16 + lm];
#pragma unroll
                for (int g = 0; g < 2; ++g) {
                    // head = 32 cols = nt in {2g, 2g+1}; RoPE pair (d, d+16) lives in same lane
                    float x1 = acc[mt][2 * g][r], x2 = acc[mt][2 * g + 1][r];
                    float ssv = x1 * x1 + x2 * x2;
#pragma unroll
                    for (int off = 8; off >= 1; off >>= 1) ssv += __shfl_xor(ssv, off, 16);
                    float rinv = rsqrtf(ssv * (1.0f / 32.0f) + 1e-6f);
                    x1 *= rinv; x2 *= rinv;
                    float o1 = x1 * c - x2 * s;
                    float o2 = x2 * c + x1 * s;
                    int hh = (n0 + wn * 64 + g * 32) >> 5;
                    if (z == 0) { float gs = gain[hh] * QSCALE; o1 *= gs; o2 *= gs; }
                    long base = ((long)(b_ * NHn + hh) * Tn + t_) * 32;
                    dst[base + lm] = f2bf(o1);
                    dst[base + 16 + lm] = f2bf(o2);
                }
            }
    }
}

// ---------------- proj GEMM (m97 pattern), fp32 out ----------------
__global__ __launch_bounds__(256) void gemm_proj(
    const unsigned short* __restrict__ A, const unsigned short* __restrict__ Bm,
    float* __restrict__ C) {
    const int m0 = blockIdx.x * 128, n0 = blockIdx.y * 128;
    const int tid = threadIdx.x, w = tid >> 6, l = tid & 63;
    const int wm = w & 1, wn = w >> 1, lm = l & 15, quad = l >> 4;

    __shared__ __align__(16) unsigned short As[128 * 32];
    __shared__ __align__(16) unsigned short Bs[128 * 32];

    f32x4 acc[4][4] = {};

    const int r0 = (w * 2 + 0) * 16 + (l >> 2);
    const int r1 = (w * 2 + 1) * 16 + (l >> 2);
    const int c0 = (l & 3) * 8;
    const unsigned short* gA0 = A + (long)(m0 + r0) * Dn + c0;
    const unsigned short* gA1 = A + (long)(m0 + r1) * Dn + c0;
    const unsigned short* gB0 = Bm + (long)(n0 + r0) * Dn + c0;
    const unsigned short* gB1 = Bm + (long)(n0 + r1) * Dn + c0;
    unsigned short* lA0 = As + (w * 2 + 0) * 16 * 32;
    unsigned short* lA1 = As + (w * 2 + 1) * 16 * 32;
    unsigned short* lB0 = Bs + (w * 2 + 0) * 16 * 32;
    unsigned short* lB1 = Bs + (w * 2 + 1) * 16 * 32;

    for (int kk = 0; kk < Dn; kk += 32) {
        __builtin_amdgcn_global_load_lds(GPTR(gA0 + kk), LPTR(lA0), 16, 0, 0);
        __builtin_amdgcn_global_load_lds(GPTR(gA1 + kk), LPTR(lA1), 16, 0, 0);
        __builtin_amdgcn_global_load_lds(GPTR(gB0 + kk), LPTR(lB0), 16, 0, 0);
        __builtin_amdgcn_global_load_lds(GPTR(gB1 + kk), LPTR(lB1), 16, 0, 0);
        __syncthreads();
        bf16x8 af[4], bfv[4];
#pragma unroll
        for (int mt = 0; mt < 4; ++mt)
            af[mt] = __builtin_bit_cast(bf16x8,
                *reinterpret_cast<const uint4*>(As + (wm * 64 + mt * 16 + lm) * 32 + quad * 8));
#pragma unroll
        for (int nt = 0; nt < 4; ++nt)
            bfv[nt] = __builtin_bit_cast(bf16x8,
                *reinterpret_cast<const uint4*>(Bs + (wn * 64 + nt * 16 + lm) * 32 + quad * 8));
#pragma unroll
        for (int mt = 0; mt < 4; ++mt)
#pragma unroll
            for (int nt = 0; nt < 4; ++nt)
                acc[mt][nt] = __builtin_amdgcn_mfma_f32_16x16x32_bf16(af[mt], bfv[nt], acc[mt][nt], 0, 0, 0);
        __syncthreads();
    }
#pragma unroll
    for (int mt = 0; mt < 4; ++mt)
#pragma unroll
        for (int nt = 0; nt < 4; ++nt)
#pragma unroll
            for (int r = 0; r < 4; ++r) {
                int rg = m0 + wm * 64 + mt * 16 + quad * 4 + r;
                int cg = n0 + wn * 64 + nt * 16 + lm;
                C[(long)rg * Dn + cg] = acc[mt][nt][r];
            }
}

// ---------------- flash attention: swapped-QK 32x32, LDS K/V, counted-vmcnt pipeline, XCD swizzle --------
// R9 post-mortem: stall-bound at the per-tile barrier. __syncthreads drains vmcnt(0) so prefetch
// depth was structurally 1: DMA got ~1 compute phase (~500cy) vs ~900cy HBM latency -> every tile
// ate a ~400cy barrier wait (VALUBusy 50%). Two fixes, both aimed at that stall:
//  (1) T4 counted-vmcnt 3-buffer pipeline: raw s_barrier + "s_waitcnt vmcnt(2)" lets stage(i+1)
//      stay in flight ACROSS the barrier (2 compute phases to land). Final iter uses vmcnt(0)
//      (FIFO tail: outstanding={S(cnt-1)} <= 2 would never wait).
//  (2) T1 XCD swizzle: id = (bhid%8) + 8*bx + 64*(bhid/8) puts all 8 same-(b,h) blocks on ONE
//      XCD -> per-XCD K/V working set 8 heads x 256KB = 2MB, L2-resident -> staging latency ~3x lower.
// Structure otherwise = R9 (verified): 8 waves = 4 q-waves x 2 k-groups, uniform paired blocks,
// static-M linear partial combine. Plain __launch_bounds__ (R2 lesson: never force VGPR cap).
__global__ __launch_bounds__(512) void attn(
    const unsigned short* __restrict__ Qn, const unsigned short* __restrict__ Kn,
    const unsigned short* __restrict__ Vt, unsigned short* __restrict__ Y) {
    const int id = blockIdx.x;
    const int bx = (id >> 3) & 7;                       // q-slot 0..7
    const int bhid = ((id >> 6) << 3) | (id & 7);       // same-(b,h) blocks share id%8 -> same XCD
    const int b = bhid >> 5, h = bhid & 31;
    const int tid = threadIdx.x, w = tid >> 6, l = tid & 63;
    const int wq = w & 3, kg = w >> 2;
    const int lr = l & 31, hf = l >> 5;  // lane-row (q-row / d), half-select
    const long bh = b * NHn + h;
    const unsigned short* Qh = Qn + bh * Tn * 32;
    const unsigned short* Kh = Kn + bh * Tn * 32;
    const unsigned short* Vh = Vt + bh * 32 * Tn;

    __shared__ __align__(16) unsigned short KT[2][3][2048];  // [kg][buf]: 64 k-rows x 64B, slot-permuted
    __shared__ __align__(16) unsigned short VT[2][3][2048];  // [kg][buf]: 32 d-rows x 128B, slot-permuted
    __shared__ float Po[4][64][17];                          // k-group partial exchange (o[16] + lsum)

    // ---- static per-lane DMA source offsets (inverse permutation; wq-based, same per group) ----
    const int k_row = wq * 16 + (l >> 2);
    const int k_s = ((l & 3) - (k_row >> 1)) & 3;
    const unsigned short* ksrc = Kh + k_row * 32 + k_s * 8;  // + k0*32 per tile
    const int v_row = wq * 8 + (l >> 3);
    const int v_s = ((l & 7) - v_row) & 7;
    const unsigned short* vsrc = Vh + (long)v_row * Tn + v_s * 8;  // + k0 per tile

    for (int pass = 0; pass < 2; ++pass) {
        const int qb = pass ? (15 - bx) : bx;
        const int q0 = qb * 128 + wq * 32;

        // Q fragments (B-operand of swapped QK^T): lane lr holds q-row q0+lr
        bf16x8 qf[2];
        qf[0] = __builtin_bit_cast(bf16x8,
            *reinterpret_cast<const uint4*>(Qh + (q0 + lr) * 32 + hf * 8));
        qf[1] = __builtin_bit_cast(bf16x8,
            *reinterpret_cast<const uint4*>(Qh + (q0 + lr) * 32 + 16 + hf * 8));
        float ss = 0.f;
#pragma unroll
        for (int j = 0; j < 8; ++j) {
            float v0 = (float)qf[0][j], v1 = (float)qf[1][j];
            ss += v0 * v0 + v1 * v1;
        }
        ss += __shfl_xor(ss, 32);
        const float Mv = __builtin_sqrtf(ss * 32.0f);  // |q_row| * |k|max (rms -> |k| <= sqrt(32))
        f32x16 negC;
#pragma unroll
        for (int i = 0; i < 16; ++i) negC[i] = -Mv;

        float lsum = 0.f;
        f32x16 o = {};  // O[qrow in regs][d = lane&31]

        const int kend = q0 + 31;
        // group tile ranges: [0, qb+1) and [qb+1, 2qb+2): equal counts -> lockstep barriers
        const int cnt = qb + 1;
        const int ts = kg ? cnt : 0;

        auto stage = [&](int buf, int kt) {
            __builtin_amdgcn_global_load_lds(GPTR(ksrc + kt * 64 * 32), LPTR(&KT[kg][buf][wq * 512]), 16, 0, 0);
            __builtin_amdgcn_global_load_lds(GPTR(vsrc + kt * 64), LPTR(&VT[kg][buf][wq * 512]), 16, 0, 0);
        };

        auto compute_t = [&](int buf, int k0) {
#pragma unroll
            for (int sub = 0; sub < 2; ++sub) {
                const int ks = k0 + sub * 32;
                if (ks > kend) continue;  // wave-uniform
                const int krow = sub * 32 + lr;
                const int sl0 = ((0 + hf) + (krow >> 1)) & 3;  // dt=0: s = hf
                const int sl1 = ((2 + hf) + (krow >> 1)) & 3;  // dt=1: s = 2+hf
                bf16x8 k0f = __builtin_bit_cast(bf16x8,
                    *reinterpret_cast<const uint4*>(&KT[kg][buf][krow * 32 + sl0 * 8]));
                bf16x8 k1f = __builtin_bit_cast(bf16x8,
                    *reinterpret_cast<const uint4*>(&KT[kg][buf][krow * 32 + sl1 * 8]));
                f32x16 st = __builtin_amdgcn_mfma_f32_32x32x16_bf16(k0f, qf[0], negC, 0, 0, 0);
                st = __builtin_amdgcn_mfma_f32_32x32x16_bf16(k1f, qf[1], st, 0, 0, 0);
                const bool full = (ks + 31) <= q0;
                const int qrow = q0 + lr;
                float p[16];
#pragma unroll
                for (int r = 0; r < 16; ++r) {
                    float pv = __builtin_amdgcn_exp2f(st[r]);
                    if (!full) {
                        int kgc = ks + (r & 3) + 8 * (r >> 2) + 4 * hf;
                        pv = (kgc <= qrow) ? pv : 0.0f;
                    }
                    p[r] = pv;
                }
                float t0 = (p[0] + p[1]) + (p[2] + p[3]);
                float t1 = (p[4] + p[5]) + (p[6] + p[7]);
                float t2 = (p[8] + p[9]) + (p[10] + p[11]);
                float t3 = (p[12] + p[13]) + (p[14] + p[15]);
                lsum += (t0 + t1) + (t2 + t3);
                unsigned A0 = pkbf(p[0], p[1]), A1 = pkbf(p[2], p[3]);
                unsigned B0 = pkbf(p[4], p[5]), B1 = pkbf(p[6], p[7]);
                unsigned A2 = pkbf(p[8], p[9]), A3 = pkbf(p[10], p[11]);
                unsigned B2 = pkbf(p[12], p[13]), B3 = pkbf(p[14], p[15]);
                u32x2 s0 = __builtin_amdgcn_permlane32_swap(A0, B0, false, false);
                u32x2 s1 = __builtin_amdgcn_permlane32_swap(A1, B1, false, false);
                u32x2 s2 = __builtin_amdgcn_permlane32_swap(A2, B2, false, false);
                u32x2 s3 = __builtin_amdgcn_permlane32_swap(A3, B3, false, false);
                uint4 f0; f0.x = s0[0]; f0.y = s1[0]; f0.z = s0[1]; f0.w = s1[1];
                uint4 f1; f1.x = s2[0]; f1.y = s3[0]; f1.z = s2[1]; f1.w = s3[1];
                const int slv0 = ((sub * 4 + 0 + hf) + lr) & 7;
                const int slv1 = ((sub * 4 + 2 + hf) + lr) & 7;
                bf16x8 v0f = __builtin_bit_cast(bf16x8,
                    *reinterpret_cast<const uint4*>(&VT[kg][buf][lr * 64 + slv0 * 8]));
                bf16x8 v1f = __builtin_bit_cast(bf16x8,
                    *reinterpret_cast<const uint4*>(&VT[kg][buf][lr * 64 + slv1 * 8]));
                o = __builtin_amdgcn_mfma_f32_32x32x16_bf16(
                    __builtin_bit_cast(bf16x8, f0), v0f, o, 0, 0, 0);
                o = __builtin_amdgcn_mfma_f32_32x32x16_bf16(
                    __builtin_bit_cast(bf16x8, f1), v1f, o, 0, 0, 0);
            }
        };

        // ---- counted-vmcnt 3-buffer pipeline: stage(i+1) stays in flight across the barrier ----
        // FIFO accounting (2 DMA/stage): before wait at iter i, outstanding = {S(i), S(i+1)}.
        // vmcnt(2) completes S(i), leaves S(i+1) flying. Last iter: outstanding = {S(cnt-1)}
        // (2 <= 2 would never wait) -> must drain with vmcnt(0).
        stage(0, ts);
        if (cnt > 1) stage(1, ts + 1);
        for (int i = 0; i < cnt; ++i) {
            if (i + 1 < cnt) asm volatile("s_waitcnt vmcnt(2)" ::: "memory");
            else             asm volatile("s_waitcnt vmcnt(0)" ::: "memory");
            __builtin_amdgcn_s_barrier();
            if (i + 2 < cnt) stage((i + 2) % 3, ts + i + 2);
            compute_t(i % 3, (ts + i) * 64);
        }

        // ---- linear partial combine across k-groups (static M => no max merge) ----
        __syncthreads();  // all compute done before Po write/read (also drains everything)
        if (kg) {
            float* p = &Po[wq][l][0];
#pragma unroll
            for (int r = 0; r < 16; ++r) p[r] = o[r];
            p[16] = lsum;
        }
        __syncthreads();
        if (!kg) {
            const float* p = &Po[wq][l][0];
            float ls = lsum + p[16];
            ls += __shfl_xor(ls, 32);
            const float inv = 1.0f / ls;
#pragma unroll
            for (int r = 0; r < 16; ++r) {
                int qr = (r & 3) + 8 * (r >> 2) + 4 * hf;
                float invr = __shfl(inv, qr);
                long base = ((long)(b * Tn + q0 + qr) * NHn + h) * 32;
                Y[base + lr] = f2bf((o[r] + p[r]) * invr);
            }
        }
        __syncthreads();  // protect Po + staging buffers before next pass reuses them
    }
}

extern "C" void kernel_launch(void* const* d_in, const int* in_sizes, int n_in,
                              void* d_out, int out_size, void* d_ws, size_t ws_size,
                              hipStream_t stream) {
    (void)in_sizes; (void)n_in; (void)out_size; (void)ws_size;
    const float* x = (const float*)d_in[0];
    const float* Wq = (const float*)d_in[1];
    const float* Wk = (const float*)d_in[2];
    const float* Wv = (const float*)d_in[3];
    const float* Wp = (const float*)d_in[4];
    const float* gain = (const float*)d_in[5];
    const float* cosp = (const float*)d_in[6];
    const float* sinp = (const float*)d_in[7];

    char* ws = (char*)d_ws;
    const size_t SZ = (size_t)Mn * Dn * 2;  // 8 MB
    unsigned short* xb = (unsigned short*)ws;
    unsigned short* wall = (unsigned short*)(ws + SZ);  // [Wq|Wk|Wv|Wp], 8 MB
    unsigned short* qn = (unsigned short*)(ws + 2 * SZ);
    unsigned short* kn = qn + (size_t)Mn * Dn;
    unsigned short* vt = kn + (size_t)Mn * Dn;
    unsigned short* ybuf = vt + (size_t)Mn * Dn;
    // total ws: 48 MB

    cast_all<<<8192, 256, 0, stream>>>(x, Wq, Wk, Wv, Wp, xb, wall);

    gemm_qkv<<<dim3(Mn / 128, Dn / 128, 3), 256, 0, stream>>>(
        xb, wall, qn, kn, vt, gain, cosp, sinp);

    attn<<<512, 512, 0, stream>>>(qn, kn, vt, ybuf);

    gemm_proj<<<dim3(Mn / 128, Dn / 128), 256, 0, stream>>>(
        ybuf, wall + (size_t)3 * Dn * Dn, (float*)d_out);
}